// Round 11
// baseline (246.145 us; speedup 1.0000x reference)
//
#include <hip/hip_runtime.h>
#include <math.h>

#define CC 256
#define NTOK 4096
#define LN_EPS 1e-5f
#define QSCALE 0.17677669529663687f  // 1/sqrt(32)
#define NBLK 256

typedef __bf16 bf16x8 __attribute__((ext_vector_type(8)));
typedef float f32x4 __attribute__((ext_vector_type(4)));
typedef unsigned short u16x8 __attribute__((ext_vector_type(8)));

__device__ __forceinline__ unsigned short f2bf(float f) {
    unsigned u = __builtin_bit_cast(unsigned, f);
    u += 0x7fff + ((u >> 16) & 1);   // RNE
    return (unsigned short)(u >> 16);
}
__device__ __forceinline__ float bf2f(unsigned short h) {
    unsigned u = ((unsigned)h) << 16;
    return __builtin_bit_cast(float, u);
}
__device__ __forceinline__ void gload16(const unsigned short* g, unsigned short* l) {
    __builtin_amdgcn_global_load_lds(
        (const __attribute__((address_space(1))) unsigned int*)(const void*)g,
        (__attribute__((address_space(3))) unsigned int*)(void*)l, 16, 0, 0);
}

// ---- device-scope generation barrier (all NBLK blocks, co-resident) -------
__device__ __forceinline__ void grid_sync(unsigned* bar) {
    __syncthreads();                       // drains vmcnt/lgkm (stores in L2)
    if (threadIdx.x == 0) {
        __threadfence();                   // agent release (wb L2)
        unsigned old = atomicAdd(bar, 1u);
        unsigned target = (old / NBLK + 1u) * NBLK;
        while (atomicAdd(bar, 0u) < target) __builtin_amdgcn_s_sleep(8);
        __threadfence();                   // agent acquire (inv L1/L2)
    }
    __syncthreads();
}

// ---------------- LayerNorm row: fp32 in -> bf16 out -----------------------
__device__ __forceinline__ void ln_row(const float* __restrict__ x, const float* __restrict__ g,
                                       const float* __restrict__ b, unsigned short* __restrict__ out,
                                       int tok, int lane) {
    const float4 v = ((const float4*)(x + (size_t)tok * CC))[lane];
    float s  = v.x + v.y + v.z + v.w;
    float ss = v.x * v.x + v.y * v.y + v.z * v.z + v.w * v.w;
    #pragma unroll
    for (int o = 32; o > 0; o >>= 1) { s += __shfl_xor(s, o); ss += __shfl_xor(ss, o); }
    float m   = s * (1.0f / CC);
    float var = ss * (1.0f / CC) - m * m;
    float r   = rsqrtf(var + LN_EPS);
    float4 gv = ((const float4*)g)[lane];
    float4 bv = ((const float4*)b)[lane];
    ushort4 o4;
    o4.x = f2bf((v.x - m) * r * gv.x + bv.x);
    o4.y = f2bf((v.y - m) * r * gv.y + bv.y);
    o4.z = f2bf((v.z - m) * r * gv.z + bv.z);
    o4.w = f2bf((v.w - m) * r * gv.w + bv.w);
    ((ushort4*)(out + (size_t)tok * CC))[lane] = o4;
}

// -------- GEMM tile: 3-buffer counted-vmcnt pipeline (proven R10 body) -----
template<int BM, int BN, int KD, int ACT, bool ADD_RES, bool OUT_BF16>
__device__ void gemm_tile(char* smem, const unsigned short* __restrict__ A,
                          const unsigned short* __restrict__ Bt,
                          const float* __restrict__ bias, const float* __restrict__ res,
                          void* __restrict__ Cm, int N, int bm, int bn) {
    constexpr int WM = BM / 2, WN = BN / 2;
    constexpr int MF = WM / 16, NF = WN / 16;
    constexpr int NIT = KD / 64;
    constexpr int LA = BM * 8 / 256;
    constexpr int LB = BN * 8 / 256;
    constexpr int L  = LA + LB;
    constexpr int BUFE = (BM + BN) * 64;    // u16 per buffer
    unsigned short* lds = (unsigned short*)smem;
    const int t = threadIdx.x;
    const int lane = t & 63, w = t >> 6;
    const int wr = w >> 1, wc = w & 1;
    const int fr = lane & 15, sq = lane >> 4;

    auto stage = [&](int it, int buf) {
        unsigned short* La = lds + buf * BUFE;
        unsigned short* Lb = La + BM * 64;
        #pragma unroll
        for (int i = 0; i < LA; i++) {
            int c = t + i * 256;
            int kk = c / (BM * 4), r = (c % (BM * 4)) >> 2, jj = c & 3;
            gload16(A + (size_t)(bm + r) * KD + it * 64 + kk * 32 + jj * 8, La + c * 8);
        }
        #pragma unroll
        for (int i = 0; i < LB; i++) {
            int c = t + i * 256;
            int kk = c / (BN * 4), r = (c % (BN * 4)) >> 2, jj = c & 3;
            gload16(Bt + (size_t)(bn + r) * KD + it * 64 + kk * 32 + jj * 8, Lb + c * 8);
        }
    };

    f32x4 acc[MF][NF] = {};
    stage(0, 0);
    stage(1, 1);
    for (int it = 0; it < NIT; ++it) {
        if (it < NIT - 1) {
            if constexpr (L == 4) asm volatile("s_waitcnt vmcnt(4)" ::: "memory");
            else asm volatile("s_waitcnt vmcnt(3)" ::: "memory");
        } else {
            asm volatile("s_waitcnt vmcnt(0)" ::: "memory");
        }
        __builtin_amdgcn_s_barrier();
        if (it + 2 < NIT) stage(it + 2, (it + 2) % 3);
        const char* Lab = (const char*)(lds + (it % 3) * BUFE);
        #pragma unroll
        for (int kk = 0; kk < 2; kk++) {
            const char* La = Lab + kk * BM * 64;
            const char* Lb = Lab + BM * 128 + kk * BN * 64;
            bf16x8 af[MF], bfr[NF];
            #pragma unroll
            for (int i = 0; i < MF; i++)
                af[i] = *(const bf16x8*)(La + (wr * WM + i * 16 + fr) * 64 + sq * 16);
            #pragma unroll
            for (int j = 0; j < NF; j++)
                bfr[j] = *(const bf16x8*)(Lb + (wc * WN + j * 16 + fr) * 64 + sq * 16);
            #pragma unroll
            for (int i = 0; i < MF; i++)
                #pragma unroll
                for (int j = 0; j < NF; j++)
                    acc[i][j] = __builtin_amdgcn_mfma_f32_16x16x32_bf16(af[i], bfr[j], acc[i][j], 0, 0, 0);
        }
    }
    // epilogue: C/D layout col=lane&15, row=(lane>>4)*4+reg
    #pragma unroll
    for (int i = 0; i < MF; i++) {
        int row0 = bm + wr * WM + i * 16 + sq * 4;
        #pragma unroll
        for (int j = 0; j < NF; j++) {
            int col = bn + wc * WN + j * 16 + fr;
            float bvv = bias[col];
            #pragma unroll
            for (int r = 0; r < 4; r++) {
                float v = acc[i][j][r] + bvv;
                if constexpr (ACT == 1) v = 0.5f * v * (1.0f + erff(v * 0.70710678118654752f));
                if constexpr (ADD_RES) v += res[(size_t)(row0 + r) * N + col];
                if constexpr (OUT_BF16)
                    ((unsigned short*)Cm)[(size_t)(row0 + r) * N + col] = f2bf(v);
                else
                    ((float*)Cm)[(size_t)(row0 + r) * N + col] = v;
            }
        }
    }
    asm volatile("s_waitcnt vmcnt(0)" ::: "memory");   // drain stores before next tile
    __syncthreads();
}

// ---------------- attention unit (proven R10 body, unit = old blockIdx) ----
__device__ void attn_unit(char* smem, const unsigned short* __restrict__ qkv,
                          const float* __restrict__ rpb, unsigned short* __restrict__ ctx,
                          int unit) {
    unsigned short* VT  = (unsigned short*)smem;       // [128][136]
    unsigned short* Pl  = VT + 128 * 136;              // [4][16][136]
    unsigned short* tbl = Pl + 4 * 16 * 136;           // [16][112]
    float*          rpbl = (float*)(tbl + 16 * 112);   // [4][172]

    const int t = threadIdx.x;
    const int lane = t & 63, w = t >> 6;
    const int fr = lane & 15, sq = lane >> 4;
    const int p = unit & 3, tile = (unit >> 2) & 63, hb = unit >> 8;
    const int ri = p >> 1, rj = p & 1;
    const int tgi = (tile >> 3) * 4, tgj = (tile & 7) * 4;
    const int kgi0 = min(max(tgi - 3, 0), 22);
    const int kgj0 = min(max(tgj - 3, 0), 22);
    const int head = hb * 4 + w;

    __syncthreads();                                   // protect smem reuse

    for (int i = lane; i < 169; i += 64)
        rpbl[w * 172 + i] = rpb[head * 169 + i];
    if (lane == 0) rpbl[w * 172 + 169] = -1e30f;

    for (int e = t; e < 16 * 112; e += 256) {
        int q = e / 112, kk = e % 112;
        unsigned short idx = 169;
        if (kk < 100) {
            int kr = kk / 10, kc = kk % 10;
            int qgi = tgi + (q >> 2), qgj = tgj + (q & 3);
            int kgi = kgi0 + kr, kgj = kgj0 + kc;
            int si = min(max(qgi - 3, 0), 25), sj = min(max(qgj - 3, 0), 25);
            if (kgi >= si && kgi <= si + 6 && kgj >= sj && kgj <= sj + 6)
                idx = (unsigned short)((kgi - qgi + 6) * 13 + (kgj - qgj + 6));
        }
        tbl[q * 112 + kk] = idx;
    }

    for (int c0 = t; c0 < 1600; c0 += 256) {
        int key = c0 >> 4, ch8 = c0 & 15;
        int kr = key / 10, kc = key % 10;
        int kt = ((kgi0 + kr) * 2 + ri) * 64 + (kgj0 + kc) * 2 + rj;
        u16x8 vv = *(const u16x8*)(qkv + (size_t)kt * 768 + 512 + hb * 128 + ch8 * 8);
        #pragma unroll
        for (int e = 0; e < 8; e++) VT[(ch8 * 8 + e) * 136 + key] = vv[e];
    }
    for (int c0 = t; c0 < 128 * 14; c0 += 256) {
        int row = c0 / 14, cp = c0 % 14;
        *(unsigned*)&VT[row * 136 + 100 + cp * 2] = 0;
    }
    __syncthreads();

    const int qtok = ((tgi + (fr >> 2)) * 2 + ri) * 64 + (tgj + (fr & 3)) * 2 + rj;
    bf16x8 qf = *(const bf16x8*)(qkv + (size_t)qtok * 768 + head * 32 + sq * 8);

    f32x4 sc[7];
    __builtin_amdgcn_s_setprio(1);
    #pragma unroll
    for (int c = 0; c < 7; c++) {
        int kk = c * 16 + fr;
        if (kk > 99) kk = 99;
        int kr = kk / 10, kc = kk % 10;
        int kt = ((kgi0 + kr) * 2 + ri) * 64 + (kgj0 + kc) * 2 + rj;
        bf16x8 kf = *(const bf16x8*)(qkv + (size_t)kt * 768 + 256 + head * 32 + sq * 8);
        f32x4 z = {0.0f, 0.0f, 0.0f, 0.0f};
        sc[c] = __builtin_amdgcn_mfma_f32_16x16x32_bf16(kf, qf, z, 0, 0, 0);
    }
    __builtin_amdgcn_s_setprio(0);
    #pragma unroll
    for (int c = 0; c < 7; c++)
        #pragma unroll
        for (int r = 0; r < 4; r++)
            sc[c][r] += rpbl[w * 172 + tbl[fr * 112 + c * 16 + 4 * sq + r]];

    float mx = -1e30f;
    #pragma unroll
    for (int c = 0; c < 7; c++)
        #pragma unroll
        for (int r = 0; r < 4; r++) mx = fmaxf(mx, sc[c][r]);
    mx = fmaxf(mx, __shfl_xor(mx, 16));
    mx = fmaxf(mx, __shfl_xor(mx, 32));
    float sum = 0.0f;
    #pragma unroll
    for (int c = 0; c < 7; c++)
        #pragma unroll
        for (int r = 0; r < 4; r++) {
            sc[c][r] = __expf(sc[c][r] - mx);
            sum += sc[c][r];
        }
    sum += __shfl_xor(sum, 16);
    sum += __shfl_xor(sum, 32);
    float inv = 1.0f / sum;

    #pragma unroll
    for (int c = 0; c < 7; c++)
        #pragma unroll
        for (int r = 0; r < 4; r++)
            Pl[(w * 16 + fr) * 136 + c * 16 + 4 * sq + r] = f2bf(sc[c][r] * inv);
    *(unsigned long long*)&Pl[(w * 16 + fr) * 136 + 112 + sq * 4] = 0ull;

    f32x4 o0 = {0, 0, 0, 0}, o1 = {0, 0, 0, 0};
    __builtin_amdgcn_s_setprio(1);
    #pragma unroll
    for (int m = 0; m < 4; m++) {
        bf16x8 pf = *(const bf16x8*)(&Pl[(w * 16 + fr) * 136 + m * 32 + sq * 8]);
        bf16x8 v0 = *(const bf16x8*)(&VT[(w * 32 + fr) * 136 + m * 32 + sq * 8]);
        bf16x8 v1 = *(const bf16x8*)(&VT[(w * 32 + 16 + fr) * 136 + m * 32 + sq * 8]);
        o0 = __builtin_amdgcn_mfma_f32_16x16x32_bf16(pf, v0, o0, 0, 0, 0);
        o1 = __builtin_amdgcn_mfma_f32_16x16x32_bf16(pf, v1, o1, 0, 0, 0);
    }
    __builtin_amdgcn_s_setprio(0);
    #pragma unroll
    for (int r = 0; r < 4; r++) {
        int tok = ((tgi + sq) * 2 + ri) * 64 + (tgj + r) * 2 + rj;
        ctx[(size_t)tok * 256 + head * 32 + fr]      = f2bf(o0[r]);
        ctx[(size_t)tok * 256 + head * 32 + 16 + fr] = f2bf(o1[r]);
    }
}

// ---------------- the megakernel: all 7 phases, grid-resident --------------
__global__ __launch_bounds__(256) void mega(
    const float* __restrict__ x,
    const float* __restrict__ ln1_g, const float* __restrict__ ln1_b,
    const float* __restrict__ wq, const float* __restrict__ bq,
    const float* __restrict__ wk, const float* __restrict__ bk,
    const float* __restrict__ wv, const float* __restrict__ bv,
    const float* __restrict__ rpb,
    const float* __restrict__ wo, const float* __restrict__ bo,
    const float* __restrict__ ln2_g, const float* __restrict__ ln2_b,
    const float* __restrict__ w1, const float* __restrict__ b1,
    const float* __restrict__ w2, const float* __restrict__ b2,
    unsigned short* __restrict__ hs_bf, unsigned short* __restrict__ qkv_bf,
    unsigned short* __restrict__ ctx_bf, float* __restrict__ hs2,
    unsigned short* __restrict__ y1_bf, unsigned short* __restrict__ gm_bf,
    unsigned short* __restrict__ wt_qkv, unsigned short* __restrict__ wo_t,
    unsigned short* __restrict__ w1_t, unsigned short* __restrict__ w2_t,
    float* __restrict__ bqkv, float* __restrict__ out, unsigned* bar) {
    __shared__ __align__(16) char smem[58560];
    const int b = blockIdx.x;
    const int t = threadIdx.x;

    // ===== phase 0: weight transpose/convert + bias fuse + LN1 =====
    if (b < 192) {
        const float* src; unsigned short* dst;
        int Kd, N, rowoff = 0, bx, by; float scale = 1.0f;
        if (b < 16)       { src = wq; dst = wt_qkv; Kd = 256;  N = 256;  scale = QSCALE; int l = b;       bx = l & 3;  by = l >> 2; }
        else if (b < 32)  { src = wk; dst = wt_qkv; Kd = 256;  N = 256;  rowoff = 256;   int l = b - 16;  bx = l & 3;  by = l >> 2; }
        else if (b < 48)  { src = wv; dst = wt_qkv; Kd = 256;  N = 256;  rowoff = 512;   int l = b - 32;  bx = l & 3;  by = l >> 2; }
        else if (b < 64)  { src = wo; dst = wo_t;   Kd = 256;  N = 256;                  int l = b - 48;  bx = l & 3;  by = l >> 2; }
        else if (b < 128) { src = w1; dst = w1_t;   Kd = 256;  N = 1024;                 int l = b - 64;  bx = l & 15; by = l >> 4; }
        else              { src = w2; dst = w2_t;   Kd = 1024; N = 256;                  int l = b - 128; bx = l & 3;  by = l >> 2; }
        int n0 = bx * 64, k0 = by * 64;
        float (*tile)[65] = (float(*)[65])smem;
        int cc = t & 63, rb = t >> 6;
        #pragma unroll
        for (int i = 0; i < 16; i++) {
            int r = rb + i * 4;
            tile[r][cc] = src[(size_t)(k0 + r) * N + n0 + cc];
        }
        __syncthreads();
        int n = t >> 2;
        #pragma unroll
        for (int i = 0; i < 8; i++) {
            int pp = (t & 3) + i * 4;
            unsigned lo = f2bf(tile[2 * pp][n] * scale);
            unsigned hi = f2bf(tile[2 * pp + 1][n] * scale);
            *(unsigned*)(dst + (size_t)(rowoff + n0 + n) * Kd + k0 + 2 * pp) = lo | (hi << 16);
        }
    } else if (b == 192) {
        bqkv[t]       = bq[t] * QSCALE;
        bqkv[256 + t] = bk[t];
        bqkv[512 + t] = bv[t];
    }
    #pragma unroll
    for (int k2 = 0; k2 < 4; k2++) {
        int q = b * 4 + k2;
        ln_row(x, ln1_g, ln1_b, hs_bf, q * 4 + (t >> 6), t & 63);
    }
    grid_sync(bar);

    // ===== phase 1: QKV GEMM, 768 tiles (12 x 64), 3 per block =====
    for (int k2 = 0; k2 < 3; k2++) {
        int tid = b * 3 + k2;
        gemm_tile<64, 64, 256, 0, false, true>(smem, hs_bf, wt_qkv, bqkv, nullptr,
                                               qkv_bf, 768, (tid / 12) * 64, (tid % 12) * 64);
    }
    grid_sync(bar);

    // ===== phase 2: attention, 512 units, 2 per block =====
    for (int k2 = 0; k2 < 2; k2++)
        attn_unit(smem, qkv_bf, rpb, ctx_bf, b * 2 + k2);
    grid_sync(bar);

    // ===== phase 3: WO + x residual -> hs2 (fp32), 512 tiles (4 x 128) =====
    for (int k2 = 0; k2 < 2; k2++) {
        int tid = b * 2 + k2;
        gemm_tile<32, 64, 256, 0, true, false>(smem, ctx_bf, wo_t, bo, x,
                                               hs2, 256, (tid / 4) * 32, (tid % 4) * 64);
    }
    grid_sync(bar);

    // ===== phase 4: LN2 =====
    #pragma unroll
    for (int k2 = 0; k2 < 4; k2++) {
        int q = b * 4 + k2;
        ln_row(hs2, ln2_g, ln2_b, y1_bf, q * 4 + (t >> 6), t & 63);
    }
    grid_sync(bar);

    // ===== phase 5: FF1 + gelu, 1024 tiles (16 x 64), 4 per block =====
    for (int k2 = 0; k2 < 4; k2++) {
        int tid = b * 4 + k2;
        gemm_tile<64, 64, 256, 1, false, true>(smem, y1_bf, w1_t, b1, nullptr,
                                               gm_bf, 1024, (tid / 16) * 64, (tid % 16) * 64);
    }
    grid_sync(bar);

    // ===== phase 6: FF2 + hs2 residual -> out (fp32), 512 tiles =====
    for (int k2 = 0; k2 < 2; k2++) {
        int tid = b * 2 + k2;
        gemm_tile<32, 64, 1024, 0, true, false>(smem, gm_bf, w2_t, b2, hs2,
                                                out, 256, (tid / 4) * 32, (tid % 4) * 64);
    }
}

extern "C" void kernel_launch(void* const* d_in, const int* in_sizes, int n_in,
                              void* d_out, int out_size, void* d_ws, size_t ws_size,
                              hipStream_t stream) {
    const float* x     = (const float*)d_in[0];
    const float* ln1_g = (const float*)d_in[1];
    const float* ln1_b = (const float*)d_in[2];
    const float* wq    = (const float*)d_in[3];
    const float* bq    = (const float*)d_in[4];
    const float* wk    = (const float*)d_in[5];
    const float* bk    = (const float*)d_in[6];
    const float* wv    = (const float*)d_in[7];
    const float* bv    = (const float*)d_in[8];
    const float* rpb   = (const float*)d_in[9];
    const float* wo    = (const float*)d_in[10];
    const float* bo    = (const float*)d_in[11];
    const float* ln2_g = (const float*)d_in[12];
    const float* ln2_b = (const float*)d_in[13];
    const float* w1    = (const float*)d_in[14];
    const float* b1    = (const float*)d_in[15];
    const float* w2    = (const float*)d_in[16];
    const float* b2    = (const float*)d_in[17];

    char* wsb = (char*)d_ws;
    unsigned short* hs_bf  = (unsigned short*)(wsb);                    // 2 MB
    unsigned short* qkv_bf = (unsigned short*)(wsb + (2u << 20));       // 6 MB
    unsigned short* ctx_bf = (unsigned short*)(wsb + (8u << 20));       // 2 MB
    float*          hs2    = (float*)(wsb + (10u << 20));               // 4 MB
    unsigned short* y1_bf  = (unsigned short*)(wsb + (14u << 20));      // 2 MB
    unsigned short* gm_bf  = (unsigned short*)(wsb + (16u << 20));      // 8 MB
    unsigned short* wt_qkv = (unsigned short*)(wsb + (24u << 20));      // 768x256
    unsigned short* wo_t   = wt_qkv + 768 * 256;                        // 256x256
    unsigned short* w1_t   = wo_t + 256 * 256;                          // 1024x256
    unsigned short* w2_t   = w1_t + 1024 * 256;                         // 256x1024
    float*          bqkv   = (float*)(w2_t + 256 * 1024);               // 768
    unsigned*       bar    = (unsigned*)(wsb + (40u << 20));            // barrier

    hipMemsetAsync(bar, 0, 64, stream);
    mega<<<NBLK, 256, 0, stream>>>(x, ln1_g, ln1_b, wq, bq, wk, bk, wv, bv, rpb,
                                   wo, bo, ln2_g, ln2_b, w1, b1, w2, b2,
                                   hs_bf, qkv_bf, ctx_bf, hs2, y1_bf, gm_bf,
                                   wt_qkv, wo_t, w1_t, w2_t, bqkv,
                                   (float*)d_out, bar);
}